// Round 23
// baseline (147.610 us; speedup 1.0000x reference)
//
#include <hip/hip_runtime.h>
#include <hip/hip_bf16.h>
#include <stdint.h>

#define D_MODEL 1024
#define NHEAD 16
#define DKH 64
#define BATCH 2
#define SEQ 2048
#define LOG2E 1.44269504088896f

typedef __bf16 bf16_t;
typedef __bf16 bf16x8 __attribute__((ext_vector_type(8)));
typedef float f32x4 __attribute__((ext_vector_type(4)));
typedef unsigned int u32x4 __attribute__((ext_vector_type(4)));

__device__ __forceinline__ float fast_exp2(float x) {
#if __has_builtin(__builtin_amdgcn_exp2f)
  return __builtin_amdgcn_exp2f(x);
#else
  return exp2f(x);
#endif
}

// ---------- async global->LDS (16B per lane) ----------
__device__ __forceinline__ void gload_lds16(const bf16_t* g, bf16_t* l) {
  auto gp = (const __attribute__((address_space(1))) void*)(uintptr_t)g;
  auto lp = (__attribute__((address_space(3))) void*)(uintptr_t)l;
  __builtin_amdgcn_global_load_lds(gp, lp, 16, 0, 0);
}

// ---------- non-temporal (streaming) access helpers: single-use data only ----------
__device__ __forceinline__ bf16x8 ntload_b8(const bf16_t* p) {
  u32x4 v = __builtin_nontemporal_load(reinterpret_cast<const u32x4*>(p));
  union { u32x4 u; bf16x8 b; } c; c.u = v; return c.b;
}
__device__ __forceinline__ float4 ntload_f4(const float* p) {
  u32x4 v = __builtin_nontemporal_load(reinterpret_cast<const u32x4*>(p));
  union { u32x4 u; float4 f; } c; c.u = v; return c.f;
}
__device__ __forceinline__ void ntstore_u16(bf16_t v, bf16_t* p) {
  uint16_t b; __builtin_memcpy(&b, &v, 2);
  __builtin_nontemporal_store(b, reinterpret_cast<uint16_t*>(p));
}

// Fused weight conversion -> TILED layouts (k-unit-major per 128x32 tile).
// WqkvT (j<3M): [bn(24)][kt(32)][u(4)][row(128)][e(8)] = W^T[n][d] (Q pre-scaled)
// WoT  (j>=3M): [bn(8)][kt(32)][u(4)][row(128)][e(8)] = WO[d][n]
// 8 outputs/thread (one bf16x8 store); W reads non-temporal (single use).
__global__ void k_cvtw(const float* __restrict__ WQ, const float* __restrict__ WK,
                       const float* __restrict__ WV, const float* __restrict__ WO,
                       bf16_t* __restrict__ wt) {
  size_t j = ((size_t)blockIdx.x * 256 + threadIdx.x) * 8;   // 512K threads
  bf16_t o[8];
  if (j < (size_t)3072 * 1024) {
    int bn = (int)(j >> 17), kt = (int)(j >> 12) & 31, u = (int)(j >> 10) & 3;
    int row = (int)(j >> 3) & 127;
    int n = bn * 128 + row;
    int d0 = kt * 32 + u * 8;
    int proj = n >> 10, h = (n >> 6) & 15, k = n & 63;
    const float* w = proj == 0 ? WQ : (proj == 1 ? WK : WV);
    float scale = proj == 0 ? (0.125f * LOG2E) : 1.0f;
#pragma unroll
    for (int e = 0; e < 8; e++)
      o[e] = (bf16_t)(__builtin_nontemporal_load(w + (h << 16) + ((d0 + e) << 6) + k) * scale);
  } else {
    size_t j2 = j - (size_t)3072 * 1024;
    int bn = (int)(j2 >> 17), kt = (int)(j2 >> 12) & 31, u = (int)(j2 >> 10) & 3;
    int row = (int)(j2 >> 3) & 127;
    int n = bn * 128 + row;
    int d0 = kt * 32 + u * 8;
#pragma unroll
    for (int e = 0; e < 8; e++)
      o[e] = (bf16_t)__builtin_nontemporal_load(WO + ((size_t)(d0 + e) << 10) + n);
  }
  *reinterpret_cast<bf16x8*>(wt + j) = *reinterpret_cast<bf16x8*>(o);
}

// Mask pre-gather for 16-row waves (R5-validated layout), scaled by log2e.
// M reads + Mf writes non-temporal (each element touched exactly once).
__global__ void k_maskg(const float* __restrict__ M, bf16_t* __restrict__ Mf) {
  int t = blockIdx.x * 256 + threadIdx.x;        // 1M threads, 4 vals each
  int c = t & 3, lane = (t >> 2) & 63;
  int kvt = (t >> 8) & 31, qt16 = t >> 13;
  int q = qt16 * 16 + (lane & 15);
  int kv = kvt * 64 + c * 16 + ((lane >> 4) << 2);
  float4 m4 = ntload_f4(M + (size_t)q * SEQ + kv);
  bf16_t o[4];
  o[0] = (bf16_t)(m4.x * LOG2E); o[1] = (bf16_t)(m4.y * LOG2E);
  o[2] = (bf16_t)(m4.z * LOG2E); o[3] = (bf16_t)(m4.w * LOG2E);
  uint64_t b; __builtin_memcpy(&b, o, 8);
  __builtin_nontemporal_store(b, reinterpret_cast<uint64_t*>(Mf + (size_t)t * 4));
}

// V column permutation within each 64-block (R5-validated)
__device__ __forceinline__ int vperm(int u) {
  return ((u >> 5) << 5) | (((u >> 2) & 3) << 3) | (((u >> 4) & 1) << 2) | (u & 3);
}

// ---------- fused QKV projection GEMM (R18/R21-validated, BK=32, 2-barrier) ----------
__global__ __launch_bounds__(256)
void k_gemm_qkv(const float* __restrict__ Qs, const float* __restrict__ Ks32,
                const float* __restrict__ Vs32, const bf16_t* __restrict__ Bt,
                bf16_t* __restrict__ qh, bf16_t* __restrict__ Kf,
                bf16_t* __restrict__ Vf) {
  __shared__ __align__(16) bf16_t As[4 * 128 * 8];
  __shared__ __align__(16) bf16_t Bs[4 * 128 * 8];
  const int tid = threadIdx.x;
  const int lane = tid & 63, wave = tid >> 6;
  const int g = lane >> 4, lr = lane & 15;
  const int bid = blockIdx.x;
  const int xcd = bid & 7, jj = bid >> 3;     // jj in [0,96)
  const int bm = xcd * 4 + (jj & 3);          // [0,32)
  const int bn = jj >> 2;                     // [0,24)
  const int pn = bn >> 3;   // 0:q 1:k 2:v  (block-uniform)
  const float* Ap32 = pn == 0 ? Qs : (pn == 1 ? Ks32 : Vs32);
  const bf16_t* btile = Bt + (size_t)bn * 32 * 4096;
  const int wm = (wave >> 1) << 6, wn = (wave & 1) << 6;
  const int arow = tid >> 1, au0 = (tid & 1) << 1, ako = (tid & 1) << 4;
  const float* aptr = Ap32 + (size_t)(bm * 128 + arow) * 1024 + ako;
  f32x4 acc[4][4] = {};

  float4 fA0 = *reinterpret_cast<const float4*>(aptr);
  float4 fA1 = *reinterpret_cast<const float4*>(aptr + 4);
  float4 fA2 = *reinterpret_cast<const float4*>(aptr + 8);
  float4 fA3 = *reinterpret_cast<const float4*>(aptr + 12);

  for (int kt = 0; kt < 1024; kt += 32) {
    const int ktt = kt >> 5;
#pragma unroll
    for (int cc = 0; cc < 2; cc++) {
      int c = tid + cc * 256;
      gload_lds16(btile + (size_t)ktt * 4096 + c * 8, Bs + c * 8);
    }
    {
      bf16x8 o0, o1;
      o0[0] = (bf16_t)fA0.x; o0[1] = (bf16_t)fA0.y; o0[2] = (bf16_t)fA0.z; o0[3] = (bf16_t)fA0.w;
      o0[4] = (bf16_t)fA1.x; o0[5] = (bf16_t)fA1.y; o0[6] = (bf16_t)fA1.z; o0[7] = (bf16_t)fA1.w;
      o1[0] = (bf16_t)fA2.x; o1[1] = (bf16_t)fA2.y; o1[2] = (bf16_t)fA2.z; o1[3] = (bf16_t)fA2.w;
      o1[4] = (bf16_t)fA3.x; o1[5] = (bf16_t)fA3.y; o1[6] = (bf16_t)fA3.z; o1[7] = (bf16_t)fA3.w;
      *reinterpret_cast<bf16x8*>(As + (au0 * 128 + arow) * 8) = o0;
      *reinterpret_cast<bf16x8*>(As + ((au0 + 1) * 128 + arow) * 8) = o1;
    }
    if (kt + 32 < 1024) {
      const float* np = aptr + kt + 32;
      fA0 = *reinterpret_cast<const float4*>(np);
      fA1 = *reinterpret_cast<const float4*>(np + 4);
      fA2 = *reinterpret_cast<const float4*>(np + 8);
      fA3 = *reinterpret_cast<const float4*>(np + 12);
    }
    __syncthreads();
    bf16x8 af[4], bfr[4];
#pragma unroll
    for (int t = 0; t < 4; t++)
      af[t] = *reinterpret_cast<const bf16x8*>(As + (g * 128 + wm + t * 16 + lr) * 8);
#pragma unroll
    for (int t = 0; t < 4; t++)
      bfr[t] = *reinterpret_cast<const bf16x8*>(Bs + (g * 128 + wn + t * 16 + lr) * 8);
    __builtin_amdgcn_s_setprio(1);
#pragma unroll
    for (int i = 0; i < 4; i++)
#pragma unroll
      for (int j = 0; j < 4; j++)
        acc[i][j] = __builtin_amdgcn_mfma_f32_16x16x32_bf16(af[i], bfr[j], acc[i][j], 0, 0, 0);
    __builtin_amdgcn_s_setprio(0);
    __syncthreads();
  }

#pragma unroll
  for (int i = 0; i < 4; i++)
#pragma unroll
    for (int j = 0; j < 4; j++)
#pragma unroll
      for (int e = 0; e < 4; e++) {
        int row = (bm << 7) + wm + i * 16 + g * 4 + e;       // b*SEQ + s
        int col = ((bn & 7) << 7) + wn + j * 16 + lr;        // h*64 + d
        float v = acc[i][j][e];
        int b = row >> 11, s = row & 2047, h = col >> 6, d = col & 63;
        size_t tilebase = ((size_t)(((b << 4) + h) * 32) + (s >> 6)) * 4096;
        if (pn == 0) {
          qh[((size_t)(((b << 4) + h) * SEQ + s) << 6) + d] = (bf16_t)v;
        } else if (pn == 1) {
          int r = s & 63, u = (d >> 3) ^ (r & 7), e2 = d & 7;
          Kf[tilebase + r * 64 + u * 8 + e2] = (bf16_t)v;
        } else {
          int c6 = vperm(s & 63);
          int u = (c6 >> 3) ^ (d & 7), e2 = c6 & 7;
          Vf[tilebase + d * 64 + u * 8 + e2] = (bf16_t)v;
        }
      }
}

// ---------- WO GEMM: 64x128 tiles, tiled-B k-major LDS (R18-validated) ----------
// C stores non-temporal (final output, written once).
__global__ __launch_bounds__(256)
void k_gemm_wo(const bf16_t* __restrict__ A, const bf16_t* __restrict__ Bt,
               float* __restrict__ C) {
  __shared__ __align__(16) bf16_t As[64 * 32];
  __shared__ __align__(16) bf16_t Bs[4 * 128 * 8];
  const int tid = threadIdx.x;
  const int lane = tid & 63, wave = tid >> 6;
  const int g = lane >> 4, lr = lane & 15;
  const int bid = blockIdx.x;
  const int xcd = bid & 7, jj = bid >> 3;
  const int bm = xcd * 8 + (jj & 7);
  const int bn = jj >> 3;
  const bf16_t* btile = Bt + (size_t)bn * 32 * 4096;
  const int wm = (wave >> 1) << 5, wn = (wave & 1) << 6;
  f32x4 acc[2][4] = {};

  for (int kt = 0; kt < 1024; kt += 32) {
    const int ktt = kt >> 5;
    {
      int row = tid >> 2, ko = (tid & 3) << 3;
      gload_lds16(A + (size_t)(bm * 64 + row) * 1024 + kt + ko, As + tid * 8);
    }
#pragma unroll
    for (int cc = 0; cc < 2; cc++) {
      int c = tid + cc * 256;
      gload_lds16(btile + (size_t)ktt * 4096 + c * 8, Bs + c * 8);
    }
    __syncthreads();
    bf16x8 af[2], bfr[4];
#pragma unroll
    for (int t = 0; t < 2; t++)
      af[t] = *reinterpret_cast<const bf16x8*>(As + (wm + t * 16 + lr) * 32 + g * 8);
#pragma unroll
    for (int t = 0; t < 4; t++)
      bfr[t] = *reinterpret_cast<const bf16x8*>(Bs + (g * 128 + wn + t * 16 + lr) * 8);
    __builtin_amdgcn_s_setprio(1);
#pragma unroll
    for (int i = 0; i < 2; i++)
#pragma unroll
      for (int j = 0; j < 4; j++)
        acc[i][j] = __builtin_amdgcn_mfma_f32_16x16x32_bf16(af[i], bfr[j], acc[i][j], 0, 0, 0);
    __builtin_amdgcn_s_setprio(0);
    __syncthreads();
  }
#pragma unroll
  for (int i = 0; i < 2; i++)
#pragma unroll
    for (int j = 0; j < 4; j++)
#pragma unroll
      for (int e = 0; e < 4; e++) {
        int row = (bm << 6) + wm + i * 16 + g * 4 + e;
        int col = (bn << 7) + wn + j * 16 + lr;
        __builtin_nontemporal_store(acc[i][j][e], C + (size_t)row * D_MODEL + col);
      }
}

// ---------- flash attention v4c: R17 body + non-temporal single-use streams ----------
// Mask + Q loads nt (read once -> don't evict K/V L2 hot set); O stores nt.
__global__ __launch_bounds__(512)
void k_attn4(const bf16_t* __restrict__ Qh, const bf16_t* __restrict__ Kf,
             const bf16_t* __restrict__ Vf, const bf16_t* __restrict__ Mf,
             bf16_t* __restrict__ O) {
  __shared__ __align__(16) bf16_t Ks[2][64 * 64];
  __shared__ __align__(16) bf16_t Vs[2][64 * 64];
  const int bid = blockIdx.x;
  const int xcd = bid & 7, loc = bid >> 3;
  const int bh = xcd * 4 + (loc >> 4);      // 4 bh per XCD
  const int qtile = loc & 15;
  const int b = bh >> 4, h = bh & 15;
  const int tid = threadIdx.x, wave = tid >> 6, lane = tid & 63;
  const int g = lane >> 4, lr = lane & 15;
  const int qbase = qtile * 128 + wave * 16;
  const bf16_t* qp = Qh + (size_t)bh * SEQ * DKH;
  const bf16_t* kfp = Kf + (size_t)bh * 32 * 4096;
  const bf16_t* vfp = Vf + (size_t)bh * 32 * 4096;
  const int qt16 = qtile * 8 + wave;
  const bf16_t* mp = Mf + ((size_t)qt16 * 32 * 64 + lane) * 16;

  bf16x8 aq[2];
#pragma unroll
  for (int ks = 0; ks < 2; ks++)
    aq[ks] = ntload_b8(qp + (size_t)(qbase + lr) * DKH + ks * 32 + g * 8);

  f32x4 oacc[4] = {};
  f32x4 lacc = {};
  const bf16_t onev = (bf16_t)1.0f;
  const bf16x8 ones = {onev, onev, onev, onev, onev, onev, onev, onev};

  auto stage = [&](int buf, int kt) {
    gload_lds16(kfp + (size_t)kt * 4096 + tid * 8, &Ks[buf][tid * 8]);
    gload_lds16(vfp + (size_t)kt * 4096 + tid * 8, &Vs[buf][tid * 8]);
  };

  stage(0, 0);
  bf16x8 mva = ntload_b8(mp);
  bf16x8 mvb = ntload_b8(mp + 8);
  __syncthreads();

  for (int it = 0; it < SEQ / 64; ++it) {
    const int cur = it & 1;
    if (it + 1 < SEQ / 64) stage(cur ^ 1, it + 1);
    bf16x8 mna = mva, mnb = mvb;
    if (it + 1 < SEQ / 64) {
      const bf16_t* mn = mp + (size_t)(it + 1) * 1024;
      mna = ntload_b8(mn);
      mnb = ntload_b8(mn + 8);
    }

    const bf16_t* kb = Ks[cur];
    const bf16_t* vb = Vs[cur];

    // S^T = K Q^T : D[kv=16c+4g+e][q=lr]
    f32x4 p[4];
#pragma unroll
    for (int c = 0; c < 4; c++) {
      int r = c * 16 + lr;
      bf16x8 bk0 = *reinterpret_cast<const bf16x8*>(kb + r * 64 + ((g ^ (lr & 7)) << 3));
      bf16x8 bk1 = *reinterpret_cast<const bf16x8*>(kb + r * 64 + (((4 + g) ^ (lr & 7)) << 3));
      __builtin_amdgcn_s_setprio(1);
      f32x4 a = {};
      a = __builtin_amdgcn_mfma_f32_16x16x32_bf16(bk0, aq[0], a, 0, 0, 0);
      a = __builtin_amdgcn_mfma_f32_16x16x32_bf16(bk1, aq[1], a, 0, 0, 0);
      __builtin_amdgcn_s_setprio(0);
      p[c] = a;
    }

    // mask + exp2 -> lane-local P (A-fragment order via V column permutation)
    bf16x8 pa[2];
#pragma unroll
    for (int c = 0; c < 4; c++)
#pragma unroll
      for (int e = 0; e < 4; e++) {
        int idx = c * 4 + e;
        float mk = (float)(idx < 8 ? mva[idx] : mvb[idx - 8]);
        float x = p[c][e] + mk;
        float pe = fast_exp2(fminf(x, 60.f));
        pa[c >> 1][(c & 1) * 4 + e] = (bf16_t)pe;
      }

    // row-sums via ones-MFMA
    lacc = __builtin_amdgcn_mfma_f32_16x16x32_bf16(pa[0], ones, lacc, 0, 0, 0);
    lacc = __builtin_amdgcn_mfma_f32_16x16x32_bf16(pa[1], ones, lacc, 0, 0, 0);

    // O += P V
#pragma unroll
    for (int c2 = 0; c2 < 4; c2++) {
      int r = c2 * 16 + lr;
      bf16x8 bv0 = *reinterpret_cast<const bf16x8*>(vb + r * 64 + ((g ^ (lr & 7)) << 3));
      bf16x8 bv1 = *reinterpret_cast<const bf16x8*>(vb + r * 64 + (((4 + g) ^ (lr & 7)) << 3));
      __builtin_amdgcn_s_setprio(1);
      oacc[c2] = __builtin_amdgcn_mfma_f32_16x16x32_bf16(pa[0], bv0, oacc[c2], 0, 0, 0);
      oacc[c2] = __builtin_amdgcn_mfma_f32_16x16x32_bf16(pa[1], bv1, oacc[c2], 0, 0, 0);
      __builtin_amdgcn_s_setprio(0);
    }
    __syncthreads();
    mva = mna; mvb = mnb;
  }

  float inv[4];
#pragma unroll
  for (int e = 0; e < 4; e++) inv[e] = 1.0f / lacc[e];
#pragma unroll
  for (int c2 = 0; c2 < 4; c2++)
#pragma unroll
    for (int e = 0; e < 4; e++) {
      float v = oacc[c2][e] * inv[e];
      int row = qbase + g * 4 + e;
      int col = (h << 6) + c2 * 16 + lr;
      ntstore_u16((bf16_t)v, O + (size_t)(b * SEQ + row) * D_MODEL + col);
    }
}

extern "C" void kernel_launch(void* const* d_in, const int* in_sizes, int n_in,
                              void* d_out, int out_size, void* d_ws, size_t ws_size,
                              hipStream_t stream) {
  const float* Q  = (const float*)d_in[0];
  const float* K  = (const float*)d_in[1];
  const float* V  = (const float*)d_in[2];
  const float* M  = (const float*)d_in[3];
  const float* WQ = (const float*)d_in[5];
  const float* WK = (const float*)d_in[6];
  const float* WV = (const float*)d_in[7];
  const float* WO = (const float*)d_in[8];

  char* ws = (char*)d_ws;
  const size_t MB = 1 << 20;
  bf16_t* Mf    = (bf16_t*)(ws + 24 * MB);   // 8 MB bf16 mask (16-row frag order)
  bf16_t* WqkvT = (bf16_t*)(ws + 32 * MB);   // 6 MB tiled [24][32][4][128][8]
  bf16_t* WoT   = (bf16_t*)(ws + 38 * MB);   // 2 MB tiled [8][32][4][128][8]
  bf16_t* qh    = (bf16_t*)(ws + 40 * MB);   // [B,H,S,dk]
  bf16_t* Kf    = (bf16_t*)(ws + 48 * MB);   // 8 MB K 16-frag order (LDS image)
  bf16_t* Vf    = (bf16_t*)(ws + 56 * MB);   // 8 MB V 16-frag order (LDS image)
  bf16_t* Ob    = (bf16_t*)(ws + 64 * MB);   // [B,S,H*dk]

  k_maskg<<<4096, 256, 0, stream>>>(M, Mf);
  k_cvtw<<<2048, 256, 0, stream>>>(WQ, WK, WV, WO, WqkvT);

  k_gemm_qkv<<<768, 256, 0, stream>>>(Q, K, V, WqkvT, qh, Kf, Vf);

  k_attn4<<<512, 512, 0, stream>>>(qh, Kf, Vf, Mf, Ob);

  k_gemm_wo<<<512, 256, 0, stream>>>(Ob, WoT, (float*)d_out);
}

// Round 24
// 131.164 us; speedup vs baseline: 1.1254x; 1.1254x over previous
//
#include <hip/hip_runtime.h>
#include <hip/hip_bf16.h>
#include <stdint.h>

#define D_MODEL 1024
#define NHEAD 16
#define DKH 64
#define BATCH 2
#define SEQ 2048
#define LOG2E 1.44269504088896f

typedef __bf16 bf16_t;
typedef __bf16 bf16x8 __attribute__((ext_vector_type(8)));
typedef float f32x4 __attribute__((ext_vector_type(4)));

__device__ __forceinline__ float fast_exp2(float x) {
#if __has_builtin(__builtin_amdgcn_exp2f)
  return __builtin_amdgcn_exp2f(x);
#else
  return exp2f(x);
#endif
}

// ---------- async global->LDS (16B per lane) ----------
__device__ __forceinline__ void gload_lds16(const bf16_t* g, bf16_t* l) {
  auto gp = (const __attribute__((address_space(1))) void*)(uintptr_t)g;
  auto lp = (__attribute__((address_space(3))) void*)(uintptr_t)l;
  __builtin_amdgcn_global_load_lds(gp, lp, 16, 0, 0);
}

// Fused weight conversion -> TILED layouts (k-unit-major per 128x32 tile).
// WqkvT (j<3M): [bn(24)][kt(32)][u(4)][row(128)][e(8)] = W^T[n][d] (Q pre-scaled)
// WoT  (j>=3M): [bn(8)][kt(32)][u(4)][row(128)][e(8)] = WO[d][n]
// Vectorized: 8 outputs (one bf16x8 store) per thread (R21-validated).
__global__ void k_cvtw(const float* __restrict__ WQ, const float* __restrict__ WK,
                       const float* __restrict__ WV, const float* __restrict__ WO,
                       bf16_t* __restrict__ wt) {
  size_t j = ((size_t)blockIdx.x * 256 + threadIdx.x) * 8;   // 512K threads
  bf16_t o[8];
  if (j < (size_t)3072 * 1024) {
    int bn = (int)(j >> 17), kt = (int)(j >> 12) & 31, u = (int)(j >> 10) & 3;
    int row = (int)(j >> 3) & 127;
    int n = bn * 128 + row;
    int d0 = kt * 32 + u * 8;
    int proj = n >> 10, h = (n >> 6) & 15, k = n & 63;
    const float* w = proj == 0 ? WQ : (proj == 1 ? WK : WV);
    float scale = proj == 0 ? (0.125f * LOG2E) : 1.0f;
#pragma unroll
    for (int e = 0; e < 8; e++)
      o[e] = (bf16_t)(w[(h << 16) + ((d0 + e) << 6) + k] * scale);
  } else {
    size_t j2 = j - (size_t)3072 * 1024;
    int bn = (int)(j2 >> 17), kt = (int)(j2 >> 12) & 31, u = (int)(j2 >> 10) & 3;
    int row = (int)(j2 >> 3) & 127;
    int n = bn * 128 + row;
    int d0 = kt * 32 + u * 8;
#pragma unroll
    for (int e = 0; e < 8; e++)
      o[e] = (bf16_t)WO[((size_t)(d0 + e) << 10) + n];
  }
  *reinterpret_cast<bf16x8*>(wt + j) = *reinterpret_cast<bf16x8*>(o);
}

// Mask pre-gather for 16-row waves (R5-validated layout), scaled by log2e.
__global__ void k_maskg(const float* __restrict__ M, bf16_t* __restrict__ Mf) {
  int t = blockIdx.x * 256 + threadIdx.x;        // 1M threads, 4 vals each
  int c = t & 3, lane = (t >> 2) & 63;
  int kvt = (t >> 8) & 31, qt16 = t >> 13;
  int q = qt16 * 16 + (lane & 15);
  int kv = kvt * 64 + c * 16 + ((lane >> 4) << 2);
  float4 m4 = *reinterpret_cast<const float4*>(M + (size_t)q * SEQ + kv);
  bf16_t o[4];
  o[0] = (bf16_t)(m4.x * LOG2E); o[1] = (bf16_t)(m4.y * LOG2E);
  o[2] = (bf16_t)(m4.z * LOG2E); o[3] = (bf16_t)(m4.w * LOG2E);
  *reinterpret_cast<ushort4*>(Mf + (size_t)t * 4) = *reinterpret_cast<ushort4*>(o);
}

// V column permutation within each 64-block (R5-validated)
__device__ __forceinline__ int vperm(int u) {
  return ((u >> 5) << 5) | (((u >> 2) & 3) << 3) | (((u >> 4) & 1) << 2) | (u & 3);
}

// ---------- fused QKV projection GEMM (R18/R21-validated, BK=32, 2-barrier) ----------
// 1D grid 768, XCD-clustered.  LDS tiles [u(4)][row(128)][8]: fragment reads
// at lr-stride 16B -> conflict-free; B staging linear both sides (tiled Bt).
// Epilogues: qh row-major; Kf16/Vf16 LDS-image (R17-validated).
__global__ __launch_bounds__(256)
void k_gemm_qkv(const float* __restrict__ Qs, const float* __restrict__ Ks32,
                const float* __restrict__ Vs32, const bf16_t* __restrict__ Bt,
                bf16_t* __restrict__ qh, bf16_t* __restrict__ Kf,
                bf16_t* __restrict__ Vf) {
  __shared__ __align__(16) bf16_t As[4 * 128 * 8];
  __shared__ __align__(16) bf16_t Bs[4 * 128 * 8];
  const int tid = threadIdx.x;
  const int lane = tid & 63, wave = tid >> 6;
  const int g = lane >> 4, lr = lane & 15;
  const int bid = blockIdx.x;
  const int xcd = bid & 7, jj = bid >> 3;     // jj in [0,96)
  const int bm = xcd * 4 + (jj & 3);          // [0,32)
  const int bn = jj >> 2;                     // [0,24)
  const int pn = bn >> 3;   // 0:q 1:k 2:v  (block-uniform)
  const float* Ap32 = pn == 0 ? Qs : (pn == 1 ? Ks32 : Vs32);
  const bf16_t* btile = Bt + (size_t)bn * 32 * 4096;
  const int wm = (wave >> 1) << 6, wn = (wave & 1) << 6;
  const int arow = tid >> 1, au0 = (tid & 1) << 1, ako = (tid & 1) << 4;
  const float* aptr = Ap32 + (size_t)(bm * 128 + arow) * 1024 + ako;
  f32x4 acc[4][4] = {};

  float4 fA0 = *reinterpret_cast<const float4*>(aptr);
  float4 fA1 = *reinterpret_cast<const float4*>(aptr + 4);
  float4 fA2 = *reinterpret_cast<const float4*>(aptr + 8);
  float4 fA3 = *reinterpret_cast<const float4*>(aptr + 12);

  for (int kt = 0; kt < 1024; kt += 32) {
    const int ktt = kt >> 5;
#pragma unroll
    for (int cc = 0; cc < 2; cc++) {
      int c = tid + cc * 256;
      gload_lds16(btile + (size_t)ktt * 4096 + c * 8, Bs + c * 8);
    }
    {
      bf16x8 o0, o1;
      o0[0] = (bf16_t)fA0.x; o0[1] = (bf16_t)fA0.y; o0[2] = (bf16_t)fA0.z; o0[3] = (bf16_t)fA0.w;
      o0[4] = (bf16_t)fA1.x; o0[5] = (bf16_t)fA1.y; o0[6] = (bf16_t)fA1.z; o0[7] = (bf16_t)fA1.w;
      o1[0] = (bf16_t)fA2.x; o1[1] = (bf16_t)fA2.y; o1[2] = (bf16_t)fA2.z; o1[3] = (bf16_t)fA2.w;
      o1[4] = (bf16_t)fA3.x; o1[5] = (bf16_t)fA3.y; o1[6] = (bf16_t)fA3.z; o1[7] = (bf16_t)fA3.w;
      *reinterpret_cast<bf16x8*>(As + (au0 * 128 + arow) * 8) = o0;
      *reinterpret_cast<bf16x8*>(As + ((au0 + 1) * 128 + arow) * 8) = o1;
    }
    if (kt + 32 < 1024) {
      const float* np = aptr + kt + 32;
      fA0 = *reinterpret_cast<const float4*>(np);
      fA1 = *reinterpret_cast<const float4*>(np + 4);
      fA2 = *reinterpret_cast<const float4*>(np + 8);
      fA3 = *reinterpret_cast<const float4*>(np + 12);
    }
    __syncthreads();
    bf16x8 af[4], bfr[4];
#pragma unroll
    for (int t = 0; t < 4; t++)
      af[t] = *reinterpret_cast<const bf16x8*>(As + (g * 128 + wm + t * 16 + lr) * 8);
#pragma unroll
    for (int t = 0; t < 4; t++)
      bfr[t] = *reinterpret_cast<const bf16x8*>(Bs + (g * 128 + wn + t * 16 + lr) * 8);
    __builtin_amdgcn_s_setprio(1);
#pragma unroll
    for (int i = 0; i < 4; i++)
#pragma unroll
      for (int j = 0; j < 4; j++)
        acc[i][j] = __builtin_amdgcn_mfma_f32_16x16x32_bf16(af[i], bfr[j], acc[i][j], 0, 0, 0);
    __builtin_amdgcn_s_setprio(0);
    __syncthreads();
  }

#pragma unroll
  for (int i = 0; i < 4; i++)
#pragma unroll
    for (int j = 0; j < 4; j++)
#pragma unroll
      for (int e = 0; e < 4; e++) {
        int row = (bm << 7) + wm + i * 16 + g * 4 + e;       // b*SEQ + s
        int col = ((bn & 7) << 7) + wn + j * 16 + lr;        // h*64 + d
        float v = acc[i][j][e];
        int b = row >> 11, s = row & 2047, h = col >> 6, d = col & 63;
        size_t tilebase = ((size_t)(((b << 4) + h) * 32) + (s >> 6)) * 4096;
        if (pn == 0) {
          qh[((size_t)(((b << 4) + h) * SEQ + s) << 6) + d] = (bf16_t)v;
        } else if (pn == 1) {
          int r = s & 63, u = (d >> 3) ^ (r & 7), e2 = d & 7;
          Kf[tilebase + r * 64 + u * 8 + e2] = (bf16_t)v;
        } else {
          int c6 = vperm(s & 63);
          int u = (c6 >> 3) ^ (d & 7), e2 = c6 & 7;
          Vf[tilebase + d * 64 + u * 8 + e2] = (bf16_t)v;
        }
      }
}

// ---------- WO GEMM: 64x128 tiles, tiled-B k-major LDS (R18-validated) ----------
__global__ __launch_bounds__(256)
void k_gemm_wo(const bf16_t* __restrict__ A, const bf16_t* __restrict__ Bt,
               float* __restrict__ C) {
  __shared__ __align__(16) bf16_t As[64 * 32];
  __shared__ __align__(16) bf16_t Bs[4 * 128 * 8];
  const int tid = threadIdx.x;
  const int lane = tid & 63, wave = tid >> 6;
  const int g = lane >> 4, lr = lane & 15;
  const int bid = blockIdx.x;
  const int xcd = bid & 7, jj = bid >> 3;
  const int bm = xcd * 8 + (jj & 7);
  const int bn = jj >> 3;
  const bf16_t* btile = Bt + (size_t)bn * 32 * 4096;
  const int wm = (wave >> 1) << 5, wn = (wave & 1) << 6;
  f32x4 acc[2][4] = {};

  for (int kt = 0; kt < 1024; kt += 32) {
    const int ktt = kt >> 5;
    {
      int row = tid >> 2, ko = (tid & 3) << 3;
      gload_lds16(A + (size_t)(bm * 64 + row) * 1024 + kt + ko, As + tid * 8);
    }
#pragma unroll
    for (int cc = 0; cc < 2; cc++) {
      int c = tid + cc * 256;
      gload_lds16(btile + (size_t)ktt * 4096 + c * 8, Bs + c * 8);
    }
    __syncthreads();
    bf16x8 af[2], bfr[4];
#pragma unroll
    for (int t = 0; t < 2; t++)
      af[t] = *reinterpret_cast<const bf16x8*>(As + (wm + t * 16 + lr) * 32 + g * 8);
#pragma unroll
    for (int t = 0; t < 4; t++)
      bfr[t] = *reinterpret_cast<const bf16x8*>(Bs + (g * 128 + wn + t * 16 + lr) * 8);
    __builtin_amdgcn_s_setprio(1);
#pragma unroll
    for (int i = 0; i < 2; i++)
#pragma unroll
      for (int j = 0; j < 4; j++)
        acc[i][j] = __builtin_amdgcn_mfma_f32_16x16x32_bf16(af[i], bfr[j], acc[i][j], 0, 0, 0);
    __builtin_amdgcn_s_setprio(0);
    __syncthreads();
  }
#pragma unroll
  for (int i = 0; i < 2; i++)
#pragma unroll
    for (int j = 0; j < 4; j++)
#pragma unroll
      for (int e = 0; e < 4; e++) {
        int row = (bm << 6) + wm + i * 16 + g * 4 + e;
        int col = (bn << 7) + wn + j * 16 + lr;
        C[(size_t)row * D_MODEL + col] = acc[i][j][e];
      }
}

// ---------- flash attention v4b: R17-validated (unchanged) ----------
__global__ __launch_bounds__(512)
void k_attn4(const bf16_t* __restrict__ Qh, const bf16_t* __restrict__ Kf,
             const bf16_t* __restrict__ Vf, const bf16_t* __restrict__ Mf,
             bf16_t* __restrict__ O) {
  __shared__ __align__(16) bf16_t Ks[2][64 * 64];
  __shared__ __align__(16) bf16_t Vs[2][64 * 64];
  const int bid = blockIdx.x;
  const int xcd = bid & 7, loc = bid >> 3;
  const int bh = xcd * 4 + (loc >> 4);      // 4 bh per XCD
  const int qtile = loc & 15;
  const int b = bh >> 4, h = bh & 15;
  const int tid = threadIdx.x, wave = tid >> 6, lane = tid & 63;
  const int g = lane >> 4, lr = lane & 15;
  const int qbase = qtile * 128 + wave * 16;
  const bf16_t* qp = Qh + (size_t)bh * SEQ * DKH;
  const bf16_t* kfp = Kf + (size_t)bh * 32 * 4096;
  const bf16_t* vfp = Vf + (size_t)bh * 32 * 4096;
  const int qt16 = qtile * 8 + wave;
  const bf16_t* mp = Mf + ((size_t)qt16 * 32 * 64 + lane) * 16;

  bf16x8 aq[2];
#pragma unroll
  for (int ks = 0; ks < 2; ks++)
    aq[ks] = *reinterpret_cast<const bf16x8*>(
        qp + (size_t)(qbase + lr) * DKH + ks * 32 + g * 8);

  f32x4 oacc[4] = {};
  f32x4 lacc = {};
  const bf16_t onev = (bf16_t)1.0f;
  const bf16x8 ones = {onev, onev, onev, onev, onev, onev, onev, onev};

  auto stage = [&](int buf, int kt) {
    gload_lds16(kfp + (size_t)kt * 4096 + tid * 8, &Ks[buf][tid * 8]);
    gload_lds16(vfp + (size_t)kt * 4096 + tid * 8, &Vs[buf][tid * 8]);
  };

  stage(0, 0);
  bf16x8 mva = *reinterpret_cast<const bf16x8*>(mp);
  bf16x8 mvb = *reinterpret_cast<const bf16x8*>(mp + 8);
  __syncthreads();

  for (int it = 0; it < SEQ / 64; ++it) {
    const int cur = it & 1;
    if (it + 1 < SEQ / 64) stage(cur ^ 1, it + 1);
    bf16x8 mna = mva, mnb = mvb;
    if (it + 1 < SEQ / 64) {
      const bf16_t* mn = mp + (size_t)(it + 1) * 1024;
      mna = *reinterpret_cast<const bf16x8*>(mn);
      mnb = *reinterpret_cast<const bf16x8*>(mn + 8);
    }

    const bf16_t* kb = Ks[cur];
    const bf16_t* vb = Vs[cur];

    // S^T = K Q^T : D[kv=16c+4g+e][q=lr]
    f32x4 p[4];
#pragma unroll
    for (int c = 0; c < 4; c++) {
      int r = c * 16 + lr;
      bf16x8 bk0 = *reinterpret_cast<const bf16x8*>(kb + r * 64 + ((g ^ (lr & 7)) << 3));
      bf16x8 bk1 = *reinterpret_cast<const bf16x8*>(kb + r * 64 + (((4 + g) ^ (lr & 7)) << 3));
      __builtin_amdgcn_s_setprio(1);
      f32x4 a = {};
      a = __builtin_amdgcn_mfma_f32_16x16x32_bf16(bk0, aq[0], a, 0, 0, 0);
      a = __builtin_amdgcn_mfma_f32_16x16x32_bf16(bk1, aq[1], a, 0, 0, 0);
      __builtin_amdgcn_s_setprio(0);
      p[c] = a;
    }

    // mask + exp2 -> lane-local P (A-fragment order via V column permutation)
    bf16x8 pa[2];
#pragma unroll
    for (int c = 0; c < 4; c++)
#pragma unroll
      for (int e = 0; e < 4; e++) {
        int idx = c * 4 + e;
        float mk = (float)(idx < 8 ? mva[idx] : mvb[idx - 8]);
        float x = p[c][e] + mk;
        float pe = fast_exp2(fminf(x, 60.f));
        pa[c >> 1][(c & 1) * 4 + e] = (bf16_t)pe;
      }

    // row-sums via ones-MFMA
    lacc = __builtin_amdgcn_mfma_f32_16x16x32_bf16(pa[0], ones, lacc, 0, 0, 0);
    lacc = __builtin_amdgcn_mfma_f32_16x16x32_bf16(pa[1], ones, lacc, 0, 0, 0);

    // O += P V
#pragma unroll
    for (int c2 = 0; c2 < 4; c2++) {
      int r = c2 * 16 + lr;
      bf16x8 bv0 = *reinterpret_cast<const bf16x8*>(vb + r * 64 + ((g ^ (lr & 7)) << 3));
      bf16x8 bv1 = *reinterpret_cast<const bf16x8*>(vb + r * 64 + (((4 + g) ^ (lr & 7)) << 3));
      __builtin_amdgcn_s_setprio(1);
      oacc[c2] = __builtin_amdgcn_mfma_f32_16x16x32_bf16(pa[0], bv0, oacc[c2], 0, 0, 0);
      oacc[c2] = __builtin_amdgcn_mfma_f32_16x16x32_bf16(pa[1], bv1, oacc[c2], 0, 0, 0);
      __builtin_amdgcn_s_setprio(0);
    }
    __syncthreads();
    mva = mna; mvb = mnb;
  }

  float inv[4];
#pragma unroll
  for (int e = 0; e < 4; e++) inv[e] = 1.0f / lacc[e];
#pragma unroll
  for (int c2 = 0; c2 < 4; c2++)
#pragma unroll
    for (int e = 0; e < 4; e++) {
      float v = oacc[c2][e] * inv[e];
      int row = qbase + g * 4 + e;
      int col = (h << 6) + c2 * 16 + lr;
      O[(size_t)(b * SEQ + row) * D_MODEL + col] = (bf16_t)v;
    }
}

extern "C" void kernel_launch(void* const* d_in, const int* in_sizes, int n_in,
                              void* d_out, int out_size, void* d_ws, size_t ws_size,
                              hipStream_t stream) {
  const float* Q  = (const float*)d_in[0];
  const float* K  = (const float*)d_in[1];
  const float* V  = (const float*)d_in[2];
  const float* M  = (const float*)d_in[3];
  const float* WQ = (const float*)d_in[5];
  const float* WK = (const float*)d_in[6];
  const float* WV = (const float*)d_in[7];
  const float* WO = (const float*)d_in[8];

  char* ws = (char*)d_ws;
  const size_t MB = 1 << 20;
  bf16_t* Mf    = (bf16_t*)(ws + 24 * MB);   // 8 MB bf16 mask (16-row frag order)
  bf16_t* WqkvT = (bf16_t*)(ws + 32 * MB);   // 6 MB tiled [24][32][4][128][8]
  bf16_t* WoT   = (bf16_t*)(ws + 38 * MB);   // 2 MB tiled [8][32][4][128][8]
  bf16_t* qh    = (bf16_t*)(ws + 40 * MB);   // [B,H,S,dk]
  bf16_t* Kf    = (bf16_t*)(ws + 48 * MB);   // 8 MB K 16-frag order (LDS image)
  bf16_t* Vf    = (bf16_t*)(ws + 56 * MB);   // 8 MB V 16-frag order (LDS image)
  bf16_t* Ob    = (bf16_t*)(ws + 64 * MB);   // [B,S,H*dk]

  k_maskg<<<4096, 256, 0, stream>>>(M, Mf);
  k_cvtw<<<2048, 256, 0, stream>>>(WQ, WK, WV, WO, WqkvT);

  k_gemm_qkv<<<768, 256, 0, stream>>>(Q, K, V, WqkvT, qh, Kf, Vf);

  k_attn4<<<512, 512, 0, stream>>>(qh, Kf, Vf, Mf, Ob);

  k_gemm_wo<<<512, 256, 0, stream>>>(Ob, WoT, (float*)d_out);
}